// Round 1
// baseline (594.384 us; speedup 1.0000x reference)
//
#include <hip/hip_runtime.h>

typedef unsigned short u16;
typedef unsigned int   u32;
typedef __bf16 bf16x8 __attribute__((ext_vector_type(8)));
typedef float  f32x4  __attribute__((ext_vector_type(4)));

#define NF1 768   // input feature dim
#define NF2 256   // hidden feature dim

__device__ __forceinline__ u16 f2bf(float f) {
  u32 u = __builtin_bit_cast(u32, f);
  u += 0x7fffu + ((u >> 16) & 1u);      // RTNE
  return (u16)(u >> 16);
}
__device__ __forceinline__ float bf2f(u16 h) {
  return __builtin_bit_cast(float, ((u32)h) << 16);
}
__device__ __forceinline__ u32 pack2(float a, float b) {
  return (u32)f2bf(a) | ((u32)f2bf(b) << 16);
}

// ---------------- utility ----------------
__global__ void k_zero(u32* __restrict__ p, int n) {
  int i = blockIdx.x * 256 + threadIdx.x;
  if (i < n) p[i] = 0u;
}

// W1 [768,256] f32 row-major -> W1T [256,768] bf16
__global__ void k_w1t(const float* __restrict__ W1, u16* __restrict__ W1T) {
  int idx = blockIdx.x * 256 + threadIdx.x;
  if (idx < NF1 * NF2) {
    int k = idx >> 8, j = idx & 255;
    W1T[(size_t)j * NF1 + k] = f2bf(W1[idx]);
  }
}

// ---------------- GEMM1: H1 = bf16(x @ W1), [M,256] bf16 ----------------
__global__ __launch_bounds__(256) void k_gemm(const float* __restrict__ X,
                                              const u16* __restrict__ W1T,
                                              u16* __restrict__ H1, int M) {
  __shared__ u16 lsA[128 * 64];
  __shared__ u16 lsB[128 * 64];   // B^T: [col][k]
  const int t    = threadIdx.x;
  const int m0   = blockIdx.x * 128;
  const int n0   = blockIdx.y * 128;
  const int lane = t & 63;
  const int wid  = t >> 6;
  const int wr   = wid >> 1, wc = wid & 1;
  const int r    = t >> 1;          // staging row (A) / col (B^T)
  const int h    = t & 1;           // k-half
  const int xrow = m0 + r;
  const bool arow_ok = (xrow < M);
  const float* xp = X + (size_t)xrow * NF1 + h * 32;
  const uint4* bp0 = (const uint4*)(W1T + (size_t)(n0 + r) * NF1) + h * 4;
  const int wbase = r * 64;
  const int swz   = (r & 7) << 3;   // XOR swizzle in u16 units (16B chunks)

  f32x4 acc[4][4];
  #pragma unroll
  for (int m = 0; m < 4; ++m)
    #pragma unroll
    for (int n = 0; n < 4; ++n) { f32x4 z = {0.f, 0.f, 0.f, 0.f}; acc[m][n] = z; }

  for (int kt = 0; kt < NF1 / 64; ++kt) {
    // stage A: f32 -> bf16, swizzled
    {
      uint4 wv[4];
      if (arow_ok) {
        const float4* p4 = (const float4*)(xp + kt * 64);
        #pragma unroll
        for (int c = 0; c < 4; ++c) {
          float4 v0 = p4[2 * c], v1 = p4[2 * c + 1];
          wv[c].x = pack2(v0.x, v0.y);
          wv[c].y = pack2(v0.z, v0.w);
          wv[c].z = pack2(v1.x, v1.y);
          wv[c].w = pack2(v1.z, v1.w);
        }
      } else {
        #pragma unroll
        for (int c = 0; c < 4; ++c) wv[c] = make_uint4(0, 0, 0, 0);
      }
      #pragma unroll
      for (int c = 0; c < 4; ++c) {
        int idx = wbase + ((h * 32 + c * 8) ^ swz);
        *(uint4*)(&lsA[idx]) = wv[c];
      }
    }
    // stage B^T (already bf16 in W1T)
    {
      const uint4* p = bp0 + kt * 8;
      #pragma unroll
      for (int c = 0; c < 4; ++c) {
        uint4 v = p[c];
        int idx = wbase + ((h * 32 + c * 8) ^ swz);
        *(uint4*)(&lsB[idx]) = v;
      }
    }
    __syncthreads();
    #pragma unroll
    for (int ks = 0; ks < 2; ++ks) {
      bf16x8 af[4], bfr[4];
      const int ko = ks * 32 + (lane >> 4) * 8;
      #pragma unroll
      for (int m = 0; m < 4; ++m) {
        int row = wr * 64 + m * 16 + (lane & 15);
        af[m] = *(const bf16x8*)(&lsA[row * 64 + (ko ^ ((row & 7) << 3))]);
      }
      #pragma unroll
      for (int n = 0; n < 4; ++n) {
        int col = wc * 64 + n * 16 + (lane & 15);
        bfr[n] = *(const bf16x8*)(&lsB[col * 64 + (ko ^ ((col & 7) << 3))]);
      }
      #pragma unroll
      for (int m = 0; m < 4; ++m)
        #pragma unroll
        for (int n = 0; n < 4; ++n)
          acc[m][n] = __builtin_amdgcn_mfma_f32_16x16x32_bf16(af[m], bfr[n], acc[m][n], 0, 0, 0);
    }
    __syncthreads();
  }
  // epilogue: D col=lane&15, row=(lane>>4)*4+j  (m89-verified layout)
  #pragma unroll
  for (int m = 0; m < 4; ++m) {
    int rowb = m0 + wr * 64 + m * 16 + (lane >> 4) * 4;
    #pragma unroll
    for (int n = 0; n < 4; ++n) {
      int col = n0 + wc * 64 + n * 16 + (lane & 15);
      #pragma unroll
      for (int j = 0; j < 4; ++j) {
        int row = rowb + j;
        if (row < M) H1[(size_t)row * NF2 + col] = f2bf(acc[m][n][j]);
      }
    }
  }
}

// ---------------- degree / CSR build ----------------
__global__ void k_deg(const int* __restrict__ EI, int E, u32* __restrict__ deg) {
  int e = blockIdx.x * 256 + threadIdx.x;
  if (e < E) atomicAdd(&deg[EI[E + e]], 1u);
}

__global__ __launch_bounds__(1024) void k_scan1(const u32* __restrict__ deg,
                                                u32* __restrict__ rowptr,
                                                u32* __restrict__ bsum, int Nn) {
  __shared__ u32 sm[1024];
  int t = threadIdx.x;
  int i = blockIdx.x * 1024 + t;
  u32 v = (i < Nn) ? deg[i] : 0u;
  sm[t] = v;
  __syncthreads();
  #pragma unroll
  for (int off = 1; off < 1024; off <<= 1) {
    u32 x = (t >= off) ? sm[t - off] : 0u;
    __syncthreads();
    sm[t] += x;
    __syncthreads();
  }
  u32 incl = sm[t];
  if (i < Nn) rowptr[i] = incl - v;
  if (t == 1023) bsum[blockIdx.x] = incl;
}

__global__ void k_scan2(const u32* __restrict__ bsum, u32* __restrict__ boff, int nc) {
  __shared__ u32 sm[128];
  int t = threadIdx.x;
  u32 v = (t < nc) ? bsum[t] : 0u;
  sm[t] = v;
  __syncthreads();
  #pragma unroll
  for (int off = 1; off < 128; off <<= 1) {
    u32 x = (t >= off) ? sm[t - off] : 0u;
    __syncthreads();
    sm[t] += x;
    __syncthreads();
  }
  if (t < nc) boff[t] = sm[t] - v;
}

__global__ void k_scan3(u32* __restrict__ rowptr, const u32* __restrict__ boff,
                        u32* __restrict__ cursor, const u32* __restrict__ deg,
                        float* __restrict__ dinv, int Nn, int E) {
  int i = blockIdx.x * 256 + threadIdx.x;
  if (i < Nn) {
    u32 rp = rowptr[i] + boff[i >> 10];
    rowptr[i] = rp;
    cursor[i] = rp;
    dinv[i] = rsqrtf((float)deg[i] + 1.0f);
  }
  if (i == 0) rowptr[Nn] = (u32)E;
}

__global__ void k_fill(const int* __restrict__ EI, int E, int* __restrict__ cursor,
                       int* __restrict__ csr) {
  int e = blockIdx.x * 256 + threadIdx.x;
  if (e < E) {
    int s = EI[e], d = EI[E + e];
    int pos = atomicAdd(&cursor[d], 1);
    csr[pos] = s;
  }
}

// ---------------- fused: agg1 + self + b1 + relu + @W2 -> H2 [N,2] ----------------
__global__ __launch_bounds__(256) void k_agg1(const u16* __restrict__ H1,
                                              const int* __restrict__ csr,
                                              const u32* __restrict__ rowptr,
                                              const float* __restrict__ dinv,
                                              const float* __restrict__ B1,
                                              const float* __restrict__ W2,
                                              float* __restrict__ H2, int Nn) {
  int node = (blockIdx.x << 2) + (threadIdx.x >> 6);
  if (node >= Nn) return;
  int lane = threadIdx.x & 63;
  int rp0 = (int)rowptr[node], rp1 = (int)rowptr[node + 1];
  float dvi = dinv[node];
  float a0 = 0.f, a1 = 0.f, a2 = 0.f, a3 = 0.f;
  for (int e = rp0; e < rp1; e += 2) {
    int s0 = csr[e];
    bool has1 = (e + 1 < rp1);
    int s1 = has1 ? csr[e + 1] : s0;
    float n0 = dinv[s0] * dvi;
    float n1 = has1 ? dinv[s1] * dvi : 0.f;
    ushort4 v0 = ((const ushort4*)(H1 + (size_t)s0 * NF2))[lane];
    ushort4 v1 = ((const ushort4*)(H1 + (size_t)s1 * NF2))[lane];
    a0 += n0 * bf2f(v0.x) + n1 * bf2f(v1.x);
    a1 += n0 * bf2f(v0.y) + n1 * bf2f(v1.y);
    a2 += n0 * bf2f(v0.z) + n1 * bf2f(v1.z);
    a3 += n0 * bf2f(v0.w) + n1 * bf2f(v1.w);
  }
  {   // self-loop: norm = dinv^2 = 1/deg
    float ns = dvi * dvi;
    ushort4 v = ((const ushort4*)(H1 + (size_t)node * NF2))[lane];
    a0 += ns * bf2f(v.x);
    a1 += ns * bf2f(v.y);
    a2 += ns * bf2f(v.z);
    a3 += ns * bf2f(v.w);
  }
  float4 bb = ((const float4*)B1)[lane];
  float r0 = fmaxf(a0 + bb.x, 0.f);
  float r1 = fmaxf(a1 + bb.y, 0.f);
  float r2 = fmaxf(a2 + bb.z, 0.f);
  float r3 = fmaxf(a3 + bb.w, 0.f);
  float4 wA = ((const float4*)W2)[2 * lane];       // W2[4l..4l+1][0..1]
  float4 wB = ((const float4*)W2)[2 * lane + 1];   // W2[4l+2..4l+3][0..1]
  float p0 = r0 * wA.x + r1 * wA.z + r2 * wB.x + r3 * wB.z;
  float p1 = r0 * wA.y + r1 * wA.w + r2 * wB.y + r3 * wB.w;
  #pragma unroll
  for (int o = 32; o; o >>= 1) {
    p0 += __shfl_xor(p0, o);
    p1 += __shfl_xor(p1, o);
  }
  if (lane == 0) {
    H2[2 * (size_t)node]     = p0;
    H2[2 * (size_t)node + 1] = p1;
  }
}

// ---------------- layer-2 edge aggregation, pooled directly into graph bins ----------------
__global__ __launch_bounds__(256) void k_l2e(const int* __restrict__ EI, int E,
                                             const float* __restrict__ dinv,
                                             const float* __restrict__ H2,
                                             const int* __restrict__ batch,
                                             float* __restrict__ accg) {
  __shared__ float sb[1024];
  for (int i = threadIdx.x; i < 1024; i += 256) sb[i] = 0.f;
  __syncthreads();
  for (int e = blockIdx.x * 256 + threadIdx.x; e < E; e += gridDim.x * 256) {
    int s = EI[e], d = EI[E + e];
    float nrm = dinv[s] * dinv[d];
    float2 hv = *(const float2*)(H2 + 2 * (size_t)s);
    int g = batch[d];
    atomicAdd(&sb[2 * g],     nrm * hv.x);
    atomicAdd(&sb[2 * g + 1], nrm * hv.y);
  }
  __syncthreads();
  for (int i = threadIdx.x; i < 1024; i += 256)
    if (sb[i] != 0.f) atomicAdd(&accg[i], sb[i]);
}

// layer-2 self-loop + per-graph counts
__global__ __launch_bounds__(256) void k_l2n(int Nn, const float* __restrict__ dinv,
                                             const float* __restrict__ H2,
                                             const int* __restrict__ batch,
                                             float* __restrict__ accg,
                                             u32* __restrict__ gcnt) {
  __shared__ float sb[1024];
  __shared__ u32 sc[512];
  for (int i = threadIdx.x; i < 1024; i += 256) sb[i] = 0.f;
  for (int i = threadIdx.x; i < 512; i += 256) sc[i] = 0u;
  __syncthreads();
  for (int i = blockIdx.x * 256 + threadIdx.x; i < Nn; i += gridDim.x * 256) {
    int g = batch[i];
    float dv = dinv[i];
    float ns = dv * dv;
    float2 hv = *(const float2*)(H2 + 2 * (size_t)i);
    atomicAdd(&sb[2 * g],     ns * hv.x);
    atomicAdd(&sb[2 * g + 1], ns * hv.y);
    atomicAdd(&sc[g], 1u);
  }
  __syncthreads();
  for (int i = threadIdx.x; i < 1024; i += 256)
    if (sb[i] != 0.f) atomicAdd(&accg[i], sb[i]);
  for (int i = threadIdx.x; i < 512; i += 256)
    if (sc[i]) atomicAdd(&gcnt[i], sc[i]);
}

__global__ void k_final(const float* __restrict__ accg, const u32* __restrict__ gcnt,
                        const float* __restrict__ B2, float* __restrict__ out) {
  int i = blockIdx.x * 256 + threadIdx.x;
  if (i < 1024) {
    int g = i >> 1, c = i & 1;
    float cnt = (float)gcnt[g];
    float s = accg[i] + cnt * B2[c];
    out[i] = s / fmaxf(cnt, 1.0f);
  }
}

extern "C" void kernel_launch(void* const* d_in, const int* in_sizes, int n_in,
                              void* d_out, int out_size, void* d_ws, size_t ws_size,
                              hipStream_t stream) {
  const float* X     = (const float*)d_in[0];
  const int*   EI    = (const int*)d_in[1];
  const int*   BATCH = (const int*)d_in[2];
  const float* W1    = (const float*)d_in[3];
  const float* B1    = (const float*)d_in[4];
  const float* W2    = (const float*)d_in[5];
  const float* B2    = (const float*)d_in[6];
  const int Nn = in_sizes[0] / NF1;      // 100000
  const int E  = in_sizes[1] / 2;        // 1600000
  float* OUT = (float*)d_out;
  (void)n_in; (void)out_size; (void)ws_size;

  char* w = (char*)d_ws;
  size_t off = 0;
  auto alloc = [&](size_t bytes) -> void* {
    void* p = w + off;
    off = (off + bytes + 511) & ~(size_t)511;
    return p;
  };
  u32*   deg    = (u32*)alloc((size_t)Nn * 4);
  u32*   rowptr = (u32*)alloc(((size_t)Nn + 1) * 4);
  u32*   cursor = (u32*)alloc((size_t)Nn * 4);
  u32*   bsum   = (u32*)alloc(512);
  u32*   boff   = (u32*)alloc(512);
  float* dinv   = (float*)alloc((size_t)Nn * 4);
  int*   csr    = (int*)alloc((size_t)E * 4);
  u16*   H1     = (u16*)alloc((size_t)Nn * NF2 * 2);
  float* H2     = (float*)alloc((size_t)Nn * 2 * 4);
  float* accg   = (float*)alloc(1536 * 4);   // 1024 f32 sums + 512 u32 counts
  u32*   gcnt   = (u32*)(accg + 1024);
  u16*   W1T    = (u16*)alloc((size_t)NF1 * NF2 * 2);

  const int NC = (Nn + 1023) >> 10;          // scan chunks (98), must be <= 128

  hipLaunchKernelGGL(k_zero, dim3((Nn + 255) / 256), dim3(256), 0, stream, deg, Nn);
  hipLaunchKernelGGL(k_zero, dim3(6), dim3(256), 0, stream, (u32*)accg, 1536);
  hipLaunchKernelGGL(k_w1t, dim3((NF1 * NF2 + 255) / 256), dim3(256), 0, stream, W1, W1T);
  hipLaunchKernelGGL(k_gemm, dim3((Nn + 127) / 128, 2), dim3(256), 0, stream, X, W1T, H1, Nn);
  hipLaunchKernelGGL(k_deg, dim3((E + 255) / 256), dim3(256), 0, stream, EI, E, deg);
  hipLaunchKernelGGL(k_scan1, dim3(NC), dim3(1024), 0, stream, deg, rowptr, bsum, Nn);
  hipLaunchKernelGGL(k_scan2, dim3(1), dim3(128), 0, stream, bsum, boff, NC);
  hipLaunchKernelGGL(k_scan3, dim3((Nn + 255) / 256), dim3(256), 0, stream,
                     rowptr, boff, cursor, deg, dinv, Nn, E);
  hipLaunchKernelGGL(k_fill, dim3((E + 255) / 256), dim3(256), 0, stream,
                     EI, E, (int*)cursor, csr);
  hipLaunchKernelGGL(k_agg1, dim3((Nn + 3) / 4), dim3(256), 0, stream,
                     H1, csr, rowptr, dinv, B1, W2, H2, Nn);
  hipLaunchKernelGGL(k_l2e, dim3(512), dim3(256), 0, stream, EI, E, dinv, H2, BATCH, accg);
  hipLaunchKernelGGL(k_l2n, dim3(256), dim3(256), 0, stream, Nn, dinv, H2, BATCH, accg, gcnt);
  hipLaunchKernelGGL(k_final, dim3(4), dim3(256), 0, stream, accg, gcnt, B2, OUT);
}